// Round 1
// 396.789 us; speedup vs baseline: 6.3900x; 6.3900x over previous
//
#include <hip/hip_runtime.h>

namespace {
constexpr int NN = 100000;
constexpr int NE = 600000;
constexpr int H  = 128;
constexpr int SCAN_B = 256;
constexpr int NBLK_SCAN = (NN + SCAN_B - 1) / SCAN_B;  // 391

__global__ __launch_bounds__(256) void write_marker(float* __restrict__ out,
                                                    int n, float val) {
  int i = blockIdx.x * 256 + threadIdx.x;
  if (i < n) out[i] = val;
}

// ---------------- fallback (previous verified atomic path) ----------------

__global__ __launch_bounds__(256) void zero_f4(float4* __restrict__ p, int n4) {
  int i = blockIdx.x * 256 + threadIdx.x;
  if (i < n4) p[i] = float4{0.f, 0.f, 0.f, 0.f};
}

__global__ __launch_bounds__(256) void scatter_l1(
    const int* __restrict__ src, const int* __restrict__ dst,
    const int* __restrict__ node_id, const float* __restrict__ embed,
    const float* __restrict__ norm, float* __restrict__ agg) {
  int idx = blockIdx.x * 256 + threadIdx.x;
  int e = idx >> 5;
  if (e >= NE) return;
  int c = (idx & 31) << 2;
  int s = src[e];
  float nrm = norm[s];
  const float4 v = *reinterpret_cast<const float4*>(embed + (size_t)node_id[s] * H + c);
  float* o = agg + (size_t)dst[e] * H + c;
  atomicAdd(o + 0, v.x * nrm);
  atomicAdd(o + 1, v.y * nrm);
  atomicAdd(o + 2, v.z * nrm);
  atomicAdd(o + 3, v.w * nrm);
}

__global__ __launch_bounds__(256) void scatter_l2(
    const int* __restrict__ src, const int* __restrict__ dst,
    const float* __restrict__ h1, const float* __restrict__ norm,
    float* __restrict__ agg) {
  int idx = blockIdx.x * 256 + threadIdx.x;
  int e = idx >> 5;
  if (e >= NE) return;
  int c = (idx & 31) << 2;
  int s = src[e];
  float nrm = norm[s];
  const float4 v = *reinterpret_cast<const float4*>(h1 + (size_t)s * H + c);
  float* o = agg + (size_t)dst[e] * H + c;
  atomicAdd(o + 0, v.x * nrm);
  atomicAdd(o + 1, v.y * nrm);
  atomicAdd(o + 2, v.z * nrm);
  atomicAdd(o + 3, v.w * nrm);
}

__global__ __launch_bounds__(128) void row_gemm_act(
    const float* __restrict__ agg, const float* __restrict__ W,
    const float* __restrict__ norm, const float* __restrict__ bias,
    float* __restrict__ out) {
  __shared__ float hs[H];
  const int row = blockIdx.x, j = threadIdx.x;
  hs[j] = agg[(size_t)row * H + j];
  __syncthreads();
  float acc = 0.f;
#pragma unroll
  for (int k = 0; k < H; ++k) acc += hs[k] * W[k * H + j];
  float v = acc * norm[row] + bias[j];
  v = v > 0.f ? v : 0.2f * v;
  out[(size_t)row * H + j] = v;
}

// ---------------- fast path: CSR build (once) + gather + tiled GEMM ----------------

__global__ __launch_bounds__(256) void zero_int(int* __restrict__ p, int n) {
  int i = blockIdx.x * 256 + threadIdx.x;
  if (i < n) p[i] = 0;
}

__global__ __launch_bounds__(256) void hist_dst(const int* __restrict__ dst,
                                                int* __restrict__ deg) {
  int e = blockIdx.x * 256 + threadIdx.x;
  if (e < NE) atomicAdd(&deg[dst[e]], 1);
}

// exclusive scan within 256-blocks; block totals to bsums
__global__ __launch_bounds__(SCAN_B) void scan1(const int* __restrict__ deg,
                                                int* __restrict__ offs,
                                                int* __restrict__ bsums) {
  __shared__ int sh[SCAN_B];
  const int t = threadIdx.x;
  const int gid = blockIdx.x * SCAN_B + t;
  int v = (gid < NN) ? deg[gid] : 0;
  sh[t] = v;
  __syncthreads();
  for (int d = 1; d < SCAN_B; d <<= 1) {
    int add = (t >= d) ? sh[t - d] : 0;
    __syncthreads();
    sh[t] += add;
    __syncthreads();
  }
  if (gid < NN) offs[gid] = sh[t] - v;  // exclusive within block
  if (t == SCAN_B - 1) bsums[blockIdx.x] = sh[t];
}

// exclusive scan of the 391 block sums (in place)
__global__ __launch_bounds__(512) void scan2(int* __restrict__ bsums) {
  __shared__ int sh[512];
  const int t = threadIdx.x;
  int v = (t < NBLK_SCAN) ? bsums[t] : 0;
  sh[t] = v;
  __syncthreads();
  for (int d = 1; d < 512; d <<= 1) {
    int add = (t >= d) ? sh[t - d] : 0;
    __syncthreads();
    sh[t] += add;
    __syncthreads();
  }
  if (t < NBLK_SCAN) bsums[t] = sh[t] - v;
}

__global__ __launch_bounds__(256) void scan3(int* __restrict__ offs,
                                             const int* __restrict__ bsums) {
  int gid = blockIdx.x * 256 + threadIdx.x;
  if (gid < NN) offs[gid] += bsums[blockIdx.x];
  if (gid == 0) offs[NN] = NE;  // total is always NE
}

__global__ __launch_bounds__(256) void fill_csr(
    const int* __restrict__ src, const int* __restrict__ dst,
    const int* __restrict__ offs, int* __restrict__ cnt, int* __restrict__ csr) {
  int e = blockIdx.x * 256 + threadIdx.x;
  if (e >= NE) return;
  int d = dst[e];
  int pos = offs[d] + atomicAdd(&cnt[d], 1);
  csr[pos] = src[e];
}

// One 32-lane group per node: walk incoming edges, accumulate h[src]*norm[src]
// in registers, write agg row once. No atomics, no pre-zeroing needed.
template <bool L1>
__global__ __launch_bounds__(256) void gather_rows(
    const int* __restrict__ offs, const int* __restrict__ csr,
    const int* __restrict__ node_id, const float* __restrict__ h,
    const float* __restrict__ norm, float* __restrict__ agg) {
  const int node = blockIdx.x * 8 + (threadIdx.x >> 5);  // NN % 8 == 0
  const int c = (threadIdx.x & 31) << 2;
  const int beg = offs[node];
  const int end = offs[node + 1];
  float4 acc{0.f, 0.f, 0.f, 0.f};
  for (int i = beg; i < end; ++i) {
    int s = csr[i];
    float nrm = norm[s];
    int row = L1 ? node_id[s] : s;
    const float4 v = *reinterpret_cast<const float4*>(h + (size_t)row * H + c);
    acc.x += v.x * nrm;
    acc.y += v.y * nrm;
    acc.z += v.z * nrm;
    acc.w += v.w * nrm;
  }
  *reinterpret_cast<float4*>(agg + (size_t)node * H + c) = acc;
}

// out[row] = LReLU((agg[row] @ W) * norm[row] + b); 32 rows/block, W in LDS.
// Thread layout: j4 = col-group (float4), r0 = row 0..7; each thread does
// rows {r0, r0+8, r0+16, r0+24} x cols {4*j4..4*j4+3}.
__global__ __launch_bounds__(256) void gemm32_act(
    const float* __restrict__ agg, const float* __restrict__ W,
    const float* __restrict__ norm, const float* __restrict__ bias,
    float* __restrict__ out) {
  __shared__ float Wld[H * H];    // 64 KB
  __shared__ float hs[32][H];     // 16 KB -> 80 KB total, 2 blocks/CU
  const int t = threadIdx.x;
  const int rowBase = blockIdx.x * 32;  // NN % 32 == 0

  const float4* W4 = reinterpret_cast<const float4*>(W);
  float4* Wld4 = reinterpret_cast<float4*>(Wld);
#pragma unroll
  for (int i = 0; i < 16; ++i) Wld4[t + i * 256] = W4[t + i * 256];

  {
    const float4* a4 = reinterpret_cast<const float4*>(agg + (size_t)rowBase * H);
    float4* hs4 = reinterpret_cast<float4*>(&hs[0][0]);
#pragma unroll
    for (int i = 0; i < 4; ++i) hs4[t + i * 256] = a4[t + i * 256];
  }
  __syncthreads();

  const int j4 = t & 31;
  const int r0 = t >> 5;  // 0..7
  float4 acc0{0.f, 0.f, 0.f, 0.f}, acc1{0.f, 0.f, 0.f, 0.f};
  float4 acc2{0.f, 0.f, 0.f, 0.f}, acc3{0.f, 0.f, 0.f, 0.f};
#pragma unroll 16
  for (int k = 0; k < H; ++k) {
    const float4 w = Wld4[k * 32 + j4];
    const float a0 = hs[r0][k];
    const float a1 = hs[r0 + 8][k];
    const float a2 = hs[r0 + 16][k];
    const float a3 = hs[r0 + 24][k];
    acc0.x += a0 * w.x; acc0.y += a0 * w.y; acc0.z += a0 * w.z; acc0.w += a0 * w.w;
    acc1.x += a1 * w.x; acc1.y += a1 * w.y; acc1.z += a1 * w.z; acc1.w += a1 * w.w;
    acc2.x += a2 * w.x; acc2.y += a2 * w.y; acc2.z += a2 * w.z; acc2.w += a2 * w.w;
    acc3.x += a3 * w.x; acc3.y += a3 * w.y; acc3.z += a3 * w.z; acc3.w += a3 * w.w;
  }

  const float4 bv = reinterpret_cast<const float4*>(bias)[j4];
#define EMIT(RR, ACC)                                                     \
  {                                                                       \
    const int row = rowBase + (RR);                                       \
    const float nrm = norm[row];                                          \
    float4 o;                                                             \
    o.x = ACC.x * nrm + bv.x; o.x = o.x > 0.f ? o.x : 0.2f * o.x;         \
    o.y = ACC.y * nrm + bv.y; o.y = o.y > 0.f ? o.y : 0.2f * o.y;         \
    o.z = ACC.z * nrm + bv.z; o.z = o.z > 0.f ? o.z : 0.2f * o.z;         \
    o.w = ACC.w * nrm + bv.w; o.w = o.w > 0.f ? o.w : 0.2f * o.w;         \
    *reinterpret_cast<float4*>(out + (size_t)row * H + j4 * 4) = o;       \
  }
  EMIT(r0, acc0)
  EMIT(r0 + 8, acc1)
  EMIT(r0 + 16, acc2)
  EMIT(r0 + 24, acc3)
#undef EMIT
}

}  // namespace

extern "C" void kernel_launch(void* const* d_in, const int* in_sizes, int n_in,
                              void* d_out, int out_size, void* d_ws, size_t ws_size,
                              hipStream_t stream) {
  float* out = (float*)d_out;                 // OUTPUT IS FP32
  const int nElem = NN * H;                   // 12.8M
  const int mkBl  = (out_size + 255) / 256;

  bool order_ok =
      (n_in == 9 && in_sizes[0] == NN && in_sizes[1] == NE && in_sizes[2] == NE &&
       in_sizes[3] == NN && in_sizes[4] == NN * H && in_sizes[5] == H * H &&
       in_sizes[6] == H && in_sizes[7] == H * H && in_sizes[8] == H);
  if (!order_ok || out_size != nElem) {
    write_marker<<<mkBl, 256, 0, stream>>>(out, out_size,
                                           (out_size != nElem) ? 300.0f : 200.0f);
    return;
  }
  if (ws_size < (size_t)nElem * 4) {
    write_marker<<<mkBl, 256, 0, stream>>>(out, out_size,
                                           2.0f + (float)(ws_size >> 20));
    return;
  }

  const int* node_id = (const int*)d_in[0];
  const int* src     = (const int*)d_in[1];
  const int* dst     = (const int*)d_in[2];
  const float* norm  = (const float*)d_in[3];
  const float* embed = (const float*)d_in[4];
  const float* W1    = (const float*)d_in[5];
  const float* b1    = (const float*)d_in[6];
  const float* W2    = (const float*)d_in[7];
  const float* b2    = (const float*)d_in[8];

  float* agg = (float*)d_ws;                  // fp32 [NN,H] = 51.2 MB
  float* h1  = out;                           // d_out holds h1 between layers

  // extra CSR buffers after agg
  int* offs  = (int*)((char*)d_ws + (size_t)nElem * 4);  // NN+1
  int* cnt   = offs + (NN + 1);                          // NN
  int* csr   = cnt + NN;                                 // NE
  int* bsums = csr + NE;                                 // 512
  const size_t need =
      (size_t)nElem * 4 + ((size_t)(NN + 1) + NN + NE + 512) * 4;  // ~54.5 MB

  const int zeroNBl = (NN + 255) / 256;
  const int edgeBl  = (NE + 255) / 256;

  if (ws_size >= need) {
    // ---- build CSR by dst (shared by both layers) ----
    zero_int<<<zeroNBl, 256, 0, stream>>>(cnt, NN);           // cnt as degree
    hist_dst<<<edgeBl, 256, 0, stream>>>(dst, cnt);
    scan1<<<NBLK_SCAN, SCAN_B, 0, stream>>>(cnt, offs, bsums);
    scan2<<<1, 512, 0, stream>>>(bsums);
    scan3<<<NBLK_SCAN, 256, 0, stream>>>(offs, bsums);
    zero_int<<<zeroNBl, 256, 0, stream>>>(cnt, NN);           // reset for fill
    fill_csr<<<edgeBl, 256, 0, stream>>>(src, dst, offs, cnt, csr);

    // ---- layer 1 ----
    gather_rows<true><<<NN / 8, 256, 0, stream>>>(offs, csr, node_id, embed, norm, agg);
    gemm32_act<<<NN / 32, 256, 0, stream>>>(agg, W1, norm, b1, h1);

    // ---- layer 2 ----
    gather_rows<false><<<NN / 8, 256, 0, stream>>>(offs, csr, node_id, h1, norm, agg);
    gemm32_act<<<NN / 32, 256, 0, stream>>>(agg, W2, norm, b2, out);
    return;
  }

  // ---- fallback: previous verified atomic path ----
  const int zeroBl = (nElem / 4 + 255) / 256;
  const int scatBl = (NE * 32 + 255) / 256;

  zero_f4<<<zeroBl, 256, 0, stream>>>((float4*)agg, nElem / 4);
  scatter_l1<<<scatBl, 256, 0, stream>>>(src, dst, node_id, embed, norm, agg);
  row_gemm_act<<<NN, 128, 0, stream>>>(agg, W1, norm, b1, h1);

  zero_f4<<<zeroBl, 256, 0, stream>>>((float4*)agg, nElem / 4);
  scatter_l2<<<scatBl, 256, 0, stream>>>(src, dst, h1, norm, agg);
  row_gemm_act<<<NN, 128, 0, stream>>>(agg, W2, norm, b2, out);
}